// Round 7
// baseline (329.317 us; speedup 1.0000x reference)
//
#include <hip/hip_runtime.h>
#include <cstdint>
#include <cstddef>

#define AS1 __attribute__((address_space(1)))
#define AS3 __attribute__((address_space(3)))

typedef __bf16 bf16x8 __attribute__((ext_vector_type(8)));
typedef float  f32x4  __attribute__((ext_vector_type(4)));

#define MDIM 16384   // B*S
#define NDIM 1024    // EMBED
#define KDIM 4096    // FFN
#define NQ   8

#define BM 128
#define BN 128
#define BK 64        // bf16 elems per K-chunk (8 x 16B units per row)

// ---- merged: W2 fp32->bf16 conversion + H = relu(q@W1^T + b1) -> bf16 ----
// Grid 2048 x 256 (same natural grid for both parts; saves one dispatch).
// H-stores are NONTEMPORAL: H (134 MB) streams through L2 with zero reuse
// (round-6 gemm FETCH=149MB proves the gemm re-reads H from HBM), so skip L2
// allocation and stop evicting x/W1/W2b. W2b keeps normal stores (gemm wants
// it L2-resident). Accumulation order per output is bit-identical to prior
// rounds -> absmax stays exactly 0.015625.
#define QR2 16
__global__ __launch_bounds__(256) void qhw2_kernel(const float* __restrict__ x,
                                                   const float* __restrict__ theta,
                                                   const float* __restrict__ W1,
                                                   const float* __restrict__ b1,
                                                   const float* __restrict__ W2,
                                                   __bf16* __restrict__ H,
                                                   __bf16* __restrict__ W2b) {
    __shared__ __align__(16) float qs[QR2][NQ];
    const int t  = threadIdx.x;

    // ---- part 1: W2 conversion (this block's 2048-elem slice)
    {
        size_t base = ((size_t)blockIdx.x * 256 + t) * 8;
        float4 a = *(const float4*)(W2 + base);
        float4 b = *(const float4*)(W2 + base + 4);
        bf16x8 v;
        v[0] = (__bf16)a.x; v[1] = (__bf16)a.y; v[2] = (__bf16)a.z; v[3] = (__bf16)a.w;
        v[4] = (__bf16)b.x; v[5] = (__bf16)b.y; v[6] = (__bf16)b.z; v[7] = (__bf16)b.w;
        *(bf16x8*)(W2b + base) = v;
    }

    // ---- part 2: qh (round-6 structure: fc-half in blockIdx, 16 rows/block)
    const int fc = blockIdx.x & 1;             // f-column half
    const int r0 = (blockIdx.x >> 1) * QR2;    // row group

    if (t < QR2 * NQ) {
        const int qr = t >> 3, qi = t & 7;
        const float xv = x[(size_t)(r0 + qr) * 1024 + qi];
        qs[qr][qi] = __cosf(xv) * __cosf(theta[qi]);
    }
    __syncthreads();

    const int f0 = fc * 2048 + t * 8;
    float w[8][8];
#pragma unroll
    for (int fr = 0; fr < 8; ++fr) {
        float4 a = *(const float4*)(W1 + (size_t)(f0 + fr) * NQ);
        float4 b = *(const float4*)(W1 + (size_t)(f0 + fr) * NQ + 4);
        w[fr][0] = a.x; w[fr][1] = a.y; w[fr][2] = a.z; w[fr][3] = a.w;
        w[fr][4] = b.x; w[fr][5] = b.y; w[fr][6] = b.z; w[fr][7] = b.w;
    }
    float bias[8];
    {
        float4 a = *(const float4*)(b1 + f0);
        float4 b = *(const float4*)(b1 + f0 + 4);
        bias[0] = a.x; bias[1] = a.y; bias[2] = a.z; bias[3] = a.w;
        bias[4] = b.x; bias[5] = b.y; bias[6] = b.z; bias[7] = b.w;
    }
#pragma unroll 1
    for (int r = 0; r < QR2; ++r) {
        const float4 qa = *(const float4*)&qs[r][0];   // LDS broadcast
        const float4 qb = *(const float4*)&qs[r][4];
        float q[8] = { qa.x, qa.y, qa.z, qa.w, qb.x, qb.y, qb.z, qb.w };
        bf16x8 o;
#pragma unroll
        for (int fr = 0; fr < 8; ++fr) {
            float a = bias[fr];
#pragma unroll
            for (int i = 0; i < 8; ++i) a += q[i] * w[fr][i];
            o[fr] = (__bf16)fmaxf(a, 0.f);
        }
        __builtin_nontemporal_store(o, (bf16x8*)(H + (size_t)(r0 + r) * KDIM + f0));
    }
}

// ---------------- C[M,N] = A[M,K] * B[N,K]^T + bias, bf16 MFMA ----------------
// Round-0 kernel (best measured: 141-150 us across sessions, MfmaUtil ~40%,
// 0 bank conflicts). 256-tile counted-vmcnt rewrites (r1-r4) were within
// noise of this; structure frozen. Only change: C-stores nontemporal (C is
// write-once, never re-read -> don't evict W2b panels from L2).
// m97 structure: 128x128 block, 4 waves (2x2), each wave 64x64 = 4x4 of
// 16x16x32 MFMA. BK=64, 32 KB LDS, ~3 blocks/CU.
// XCD-affine 1-D grid: xcd=id%8, s=id/8, bn=s%8 (FASTEST), bm=xcd*16+s/8.
// LDS XOR-swizzle in 16B units: phys(row, u) = u ^ (row & 7); source-side
// pre-swizzle on the global address (global_load_lds writes linearly).
__global__ __launch_bounds__(256, 3) void gemm_bt_kernel(const __bf16* __restrict__ A,
                                                         const __bf16* __restrict__ B,
                                                         const float* __restrict__ bias,
                                                         float* __restrict__ C) {
    __shared__ __align__(16) __bf16 Al[BM * BK];
    __shared__ __align__(16) __bf16 Bl[BN * BK];

    const int tid  = threadIdx.x;
    const int wave = tid >> 6;
    const int lane = tid & 63;
    const int id   = blockIdx.x;
    const int xcd  = id & 7;
    const int s    = id >> 3;
    const int bn   = s & 7;
    const int bm   = xcd * 16 + (s >> 3);

    // ---- staging: wave stages rows [wave*32, +32) of A and B, 4 chunks of 8 rows
    const int lr = lane >> 3;            // row within 8-row chunk
    const int ul = (lane & 7) ^ lr;      // logical 16B unit to source (swizzle)
    const __bf16* gA0 = A + (size_t)(bm * BM + wave * 32 + lr) * KDIM + ul * 8;
    const __bf16* gB0 = B + (size_t)(bn * BN + wave * 32 + lr) * KDIM + ul * 8;
    __bf16* lA0 = &Al[(wave * 32) * BK];
    __bf16* lB0 = &Bl[(wave * 32) * BK];

    // ---- fragment indices (16x16x32: lane holds [m=lane&15][k=(lane>>4)*8+j])
    const int ml = lane & 15;
    const int kq = lane >> 4;            // 0..3
    const int sw = lane & 7;             // row & 7 for fragment rows
    const int wm = (wave & 1) * 64;
    const int wn = (wave >> 1) * 64;

    f32x4 acc[4][4] = {};

    for (int kt = 0; kt < KDIM; kt += BK) {
        __syncthreads();   // previous tile's reads done before overwrite
#pragma unroll
        for (int c = 0; c < 4; ++c) {
            __builtin_amdgcn_global_load_lds((AS1 void*)(gA0 + (size_t)c * 8 * KDIM + kt),
                                             (AS3 void*)(lA0 + c * 8 * BK), 16, 0, 0);
            __builtin_amdgcn_global_load_lds((AS1 void*)(gB0 + (size_t)c * 8 * KDIM + kt),
                                             (AS3 void*)(lB0 + c * 8 * BK), 16, 0, 0);
        }
        __syncthreads();   // drains vmcnt -> tiles complete
#pragma unroll
        for (int st = 0; st < 2; ++st) {  // 2 k-steps of 32
            const int u = ((st * 4 + kq) ^ sw) * 8;
            bf16x8 afrag[4], bfrag[4];
#pragma unroll
            for (int i = 0; i < 4; ++i) {
                afrag[i] = *(const bf16x8*)&Al[(wm + i * 16 + ml) * BK + u];
                bfrag[i] = *(const bf16x8*)&Bl[(wn + i * 16 + ml) * BK + u];
            }
#pragma unroll
            for (int i = 0; i < 4; ++i)
#pragma unroll
                for (int j = 0; j < 4; ++j)
                    acc[i][j] = __builtin_amdgcn_mfma_f32_16x16x32_bf16(afrag[i], bfrag[j], acc[i][j], 0, 0, 0);
        }
    }

    // ---- epilogue: 16x16 C/D layout col=lane&15, row=(lane>>4)*4+reg
    const int cm0 = bm * BM + wm;
    const int cn0 = bn * BN + wn;
#pragma unroll
    for (int j = 0; j < 4; ++j) {
        const int col = cn0 + j * 16 + ml;
        const float bv = bias[col];
#pragma unroll
        for (int i = 0; i < 4; ++i) {
            const int row0 = cm0 + i * 16 + kq * 4;
#pragma unroll
            for (int r = 0; r < 4; ++r)
                __builtin_nontemporal_store(acc[i][j][r] + bv,
                                            &C[(size_t)(row0 + r) * NDIM + col]);
        }
    }
}

extern "C" void kernel_launch(void* const* d_in, const int* in_sizes, int n_in,
                              void* d_out, int out_size, void* d_ws, size_t ws_size,
                              hipStream_t stream) {
    const float* x     = (const float*)d_in[0];
    const float* theta = (const float*)d_in[1];
    const float* W1    = (const float*)d_in[2];
    const float* b1    = (const float*)d_in[3];
    const float* W2    = (const float*)d_in[4];
    const float* b2    = (const float*)d_in[5];
    float* out = (float*)d_out;

    __bf16* H   = (__bf16*)d_ws;                                    // 128 MiB
    __bf16* W2b = (__bf16*)((char*)d_ws + (size_t)MDIM * KDIM * 2); // + 8 MiB

    qhw2_kernel<<<(MDIM / QR2) * 2, 256, 0, stream>>>(x, theta, W1, b1, W2, H, W2b);
    gemm_bt_kernel<<<(MDIM / BM) * (NDIM / BN), 256, 0, stream>>>(H, W2b, b2, out);
}

// Round 8
// 275.820 us; speedup vs baseline: 1.1940x; 1.1940x over previous
//
#include <hip/hip_runtime.h>
#include <cstdint>
#include <cstddef>

#define AS1 __attribute__((address_space(1)))
#define AS3 __attribute__((address_space(3)))

typedef __bf16 bf16x8 __attribute__((ext_vector_type(8)));
typedef float  f32x4  __attribute__((ext_vector_type(4)));

#define MDIM 16384   // B*S
#define NDIM 1024    // EMBED
#define KDIM 4096    // FFN
#define NQ   8

#define BM 128
#define BN 128
#define BK 64        // bf16 elems per K-chunk (8 x 16B units per row)

// ---- merged: W2 fp32->bf16 conversion + H = relu(q@W1^T + b1) -> bf16 ----
// Grid 2048 x 256. Plain stores everywhere: round-7 measured that nontemporal
// stores HURT (gemm C nt-stores: 149->197 us, WRITE_SIZE 71->80 GB; L2
// write-combining of partial lines beats streaming hints on gfx950).
// Accumulation order bit-identical to prior rounds -> absmax 0.015625.
#define QR2 16
__global__ __launch_bounds__(256) void qhw2_kernel(const float* __restrict__ x,
                                                   const float* __restrict__ theta,
                                                   const float* __restrict__ W1,
                                                   const float* __restrict__ b1,
                                                   const float* __restrict__ W2,
                                                   __bf16* __restrict__ H,
                                                   __bf16* __restrict__ W2b) {
    __shared__ __align__(16) float qs[QR2][NQ];
    const int t  = threadIdx.x;

    // ---- part 1: W2 conversion (this block's 2048-elem slice)
    {
        size_t base = ((size_t)blockIdx.x * 256 + t) * 8;
        float4 a = *(const float4*)(W2 + base);
        float4 b = *(const float4*)(W2 + base + 4);
        bf16x8 v;
        v[0] = (__bf16)a.x; v[1] = (__bf16)a.y; v[2] = (__bf16)a.z; v[3] = (__bf16)a.w;
        v[4] = (__bf16)b.x; v[5] = (__bf16)b.y; v[6] = (__bf16)b.z; v[7] = (__bf16)b.w;
        *(bf16x8*)(W2b + base) = v;
    }

    // ---- part 2: qh (fc-half in blockIdx, 16 rows/block for TLP)
    const int fc = blockIdx.x & 1;             // f-column half
    const int r0 = (blockIdx.x >> 1) * QR2;    // row group

    if (t < QR2 * NQ) {
        const int qr = t >> 3, qi = t & 7;
        const float xv = x[(size_t)(r0 + qr) * 1024 + qi];
        qs[qr][qi] = __cosf(xv) * __cosf(theta[qi]);
    }
    __syncthreads();

    const int f0 = fc * 2048 + t * 8;
    float w[8][8];
#pragma unroll
    for (int fr = 0; fr < 8; ++fr) {
        float4 a = *(const float4*)(W1 + (size_t)(f0 + fr) * NQ);
        float4 b = *(const float4*)(W1 + (size_t)(f0 + fr) * NQ + 4);
        w[fr][0] = a.x; w[fr][1] = a.y; w[fr][2] = a.z; w[fr][3] = a.w;
        w[fr][4] = b.x; w[fr][5] = b.y; w[fr][6] = b.z; w[fr][7] = b.w;
    }
    float bias[8];
    {
        float4 a = *(const float4*)(b1 + f0);
        float4 b = *(const float4*)(b1 + f0 + 4);
        bias[0] = a.x; bias[1] = a.y; bias[2] = a.z; bias[3] = a.w;
        bias[4] = b.x; bias[5] = b.y; bias[6] = b.z; bias[7] = b.w;
    }
#pragma unroll 1
    for (int r = 0; r < QR2; ++r) {
        const float4 qa = *(const float4*)&qs[r][0];   // LDS broadcast
        const float4 qb = *(const float4*)&qs[r][4];
        float q[8] = { qa.x, qa.y, qa.z, qa.w, qb.x, qb.y, qb.z, qb.w };
        bf16x8 o;
#pragma unroll
        for (int fr = 0; fr < 8; ++fr) {
            float a = bias[fr];
#pragma unroll
            for (int i = 0; i < 8; ++i) a += q[i] * w[fr][i];
            o[fr] = (__bf16)fmaxf(a, 0.f);
        }
        *(bf16x8*)(H + (size_t)(r0 + r) * KDIM + f0) = o;
    }
}

// ---------------- C[M,N] = A[M,K] * B[N,K]^T + bias, bf16 MFMA ----------------
// Round-0 structure (best measured: 141-150 us, MfmaUtil ~40%, 0 bank
// conflicts). Structure frozen after r1-r4 rewrites landed within noise.
// Changes vs r0: launch_bounds min-waves 3 -> 4 (grid = 1024 = exactly
// 4 blocks/CU; 4-block residency target covers the per-tile barrier-drain
// stall; VGPR cap 128 >= 72, LDS 4x32KB <= 160KB). Plain C stores (r7: nt
// stores cost +48 us via partial-line HBM RMW).
// m97 structure: 128x128 block, 4 waves (2x2), each wave 64x64 = 4x4 of
// 16x16x32 MFMA. BK=64, 32 KB LDS.
// XCD-affine 1-D grid: xcd=id%8, s=id/8, bn=s%8 (FASTEST), bm=xcd*16+s/8.
// LDS XOR-swizzle in 16B units: phys(row, u) = u ^ (row & 7); source-side
// pre-swizzle on the global address (global_load_lds writes linearly).
__global__ __launch_bounds__(256, 4) void gemm_bt_kernel(const __bf16* __restrict__ A,
                                                         const __bf16* __restrict__ B,
                                                         const float* __restrict__ bias,
                                                         float* __restrict__ C) {
    __shared__ __align__(16) __bf16 Al[BM * BK];
    __shared__ __align__(16) __bf16 Bl[BN * BK];

    const int tid  = threadIdx.x;
    const int wave = tid >> 6;
    const int lane = tid & 63;
    const int id   = blockIdx.x;
    const int xcd  = id & 7;
    const int s    = id >> 3;
    const int bn   = s & 7;
    const int bm   = xcd * 16 + (s >> 3);

    // ---- staging: wave stages rows [wave*32, +32) of A and B, 4 chunks of 8 rows
    const int lr = lane >> 3;            // row within 8-row chunk
    const int ul = (lane & 7) ^ lr;      // logical 16B unit to source (swizzle)
    const __bf16* gA0 = A + (size_t)(bm * BM + wave * 32 + lr) * KDIM + ul * 8;
    const __bf16* gB0 = B + (size_t)(bn * BN + wave * 32 + lr) * KDIM + ul * 8;
    __bf16* lA0 = &Al[(wave * 32) * BK];
    __bf16* lB0 = &Bl[(wave * 32) * BK];

    // ---- fragment indices (16x16x32: lane holds [m=lane&15][k=(lane>>4)*8+j])
    const int ml = lane & 15;
    const int kq = lane >> 4;            // 0..3
    const int sw = lane & 7;             // row & 7 for fragment rows
    const int wm = (wave & 1) * 64;
    const int wn = (wave >> 1) * 64;

    f32x4 acc[4][4] = {};

    for (int kt = 0; kt < KDIM; kt += BK) {
        __syncthreads();   // previous tile's reads done before overwrite
#pragma unroll
        for (int c = 0; c < 4; ++c) {
            __builtin_amdgcn_global_load_lds((AS1 void*)(gA0 + (size_t)c * 8 * KDIM + kt),
                                             (AS3 void*)(lA0 + c * 8 * BK), 16, 0, 0);
            __builtin_amdgcn_global_load_lds((AS1 void*)(gB0 + (size_t)c * 8 * KDIM + kt),
                                             (AS3 void*)(lB0 + c * 8 * BK), 16, 0, 0);
        }
        __syncthreads();   // drains vmcnt -> tiles complete
#pragma unroll
        for (int st = 0; st < 2; ++st) {  // 2 k-steps of 32
            const int u = ((st * 4 + kq) ^ sw) * 8;
            bf16x8 afrag[4], bfrag[4];
#pragma unroll
            for (int i = 0; i < 4; ++i) {
                afrag[i] = *(const bf16x8*)&Al[(wm + i * 16 + ml) * BK + u];
                bfrag[i] = *(const bf16x8*)&Bl[(wn + i * 16 + ml) * BK + u];
            }
#pragma unroll
            for (int i = 0; i < 4; ++i)
#pragma unroll
                for (int j = 0; j < 4; ++j)
                    acc[i][j] = __builtin_amdgcn_mfma_f32_16x16x32_bf16(afrag[i], bfrag[j], acc[i][j], 0, 0, 0);
        }
    }

    // ---- epilogue: 16x16 C/D layout col=lane&15, row=(lane>>4)*4+reg
    const int cm0 = bm * BM + wm;
    const int cn0 = bn * BN + wn;
#pragma unroll
    for (int j = 0; j < 4; ++j) {
        const int col = cn0 + j * 16 + ml;
        const float bv = bias[col];
#pragma unroll
        for (int i = 0; i < 4; ++i) {
            const int row0 = cm0 + i * 16 + kq * 4;
#pragma unroll
            for (int r = 0; r < 4; ++r)
                C[(size_t)(row0 + r) * NDIM + col] = acc[i][j][r] + bv;
        }
    }
}

extern "C" void kernel_launch(void* const* d_in, const int* in_sizes, int n_in,
                              void* d_out, int out_size, void* d_ws, size_t ws_size,
                              hipStream_t stream) {
    const float* x     = (const float*)d_in[0];
    const float* theta = (const float*)d_in[1];
    const float* W1    = (const float*)d_in[2];
    const float* b1    = (const float*)d_in[3];
    const float* W2    = (const float*)d_in[4];
    const float* b2    = (const float*)d_in[5];
    float* out = (float*)d_out;

    __bf16* H   = (__bf16*)d_ws;                                    // 128 MiB
    __bf16* W2b = (__bf16*)((char*)d_ws + (size_t)MDIM * KDIM * 2); // + 8 MiB

    qhw2_kernel<<<(MDIM / QR2) * 2, 256, 0, stream>>>(x, theta, W1, b1, W2, H, W2b);
    gemm_bt_kernel<<<(MDIM / BM) * (NDIM / BN), 256, 0, stream>>>(H, W2b, b2, out);
}

// Round 9
// 275.358 us; speedup vs baseline: 1.1960x; 1.0017x over previous
//
#include <hip/hip_runtime.h>
#include <cstdint>
#include <cstddef>

#define AS1 __attribute__((address_space(1)))
#define AS3 __attribute__((address_space(3)))

typedef __bf16 bf16x8 __attribute__((ext_vector_type(8)));
typedef float  f32x4  __attribute__((ext_vector_type(4)));

#define MDIM 16384   // B*S
#define NDIM 1024    // EMBED
#define KDIM 4096    // FFN
#define NQ   8

#define BM 128
#define BN 128
#define BK 64        // bf16 elems per K-chunk (8 x 16B units per row)

// ---------------- W2 fp32 -> bf16 (8 elems/thread) ----------------
// Separate kernel (round-8's merge into qh cost ~13 us on the non-gemm side;
// round-6 split config measured best).
__global__ __launch_bounds__(256) void conv_w2_kernel(const float* __restrict__ W2,
                                                      __bf16* __restrict__ W2b) {
    size_t base = ((size_t)blockIdx.x * 256 + threadIdx.x) * 8;
    float4 a = *(const float4*)(W2 + base);
    float4 b = *(const float4*)(W2 + base + 4);
    bf16x8 v;
    v[0] = (__bf16)a.x; v[1] = (__bf16)a.y; v[2] = (__bf16)a.z; v[3] = (__bf16)a.w;
    v[4] = (__bf16)b.x; v[5] = (__bf16)b.y; v[6] = (__bf16)b.z; v[7] = (__bf16)b.w;
    *(bf16x8*)(W2b + base) = v;
}

// ------- H = relu( (cos(x[:, :8]) * cos(theta)) @ W1^T + b1 )  -> bf16 -------
// Round-6 TLP structure: fc-half in blockIdx (grid 2048), 16 rows/block ->
// 1024-FMA serial chain + 16 stores per thread, ~32 waves/CU cover.
// Plain stores (r7: nontemporal stores hurt). Accumulation order bit-identical
// across rounds -> absmax stays exactly 0.015625.
#define QR2 16
__global__ __launch_bounds__(256) void qh_kernel(const float* __restrict__ x,
                                                 const float* __restrict__ theta,
                                                 const float* __restrict__ W1,
                                                 const float* __restrict__ b1,
                                                 __bf16* __restrict__ H) {
    __shared__ __align__(16) float qs[QR2][NQ];
    const int t  = threadIdx.x;
    const int fc = blockIdx.x & 1;             // f-column half
    const int r0 = (blockIdx.x >> 1) * QR2;    // row group

    if (t < QR2 * NQ) {
        const int qr = t >> 3, qi = t & 7;
        const float xv = x[(size_t)(r0 + qr) * 1024 + qi];
        qs[qr][qi] = __cosf(xv) * __cosf(theta[qi]);
    }
    __syncthreads();

    const int f0 = fc * 2048 + t * 8;
    float w[8][8];
#pragma unroll
    for (int fr = 0; fr < 8; ++fr) {
        float4 a = *(const float4*)(W1 + (size_t)(f0 + fr) * NQ);
        float4 b = *(const float4*)(W1 + (size_t)(f0 + fr) * NQ + 4);
        w[fr][0] = a.x; w[fr][1] = a.y; w[fr][2] = a.z; w[fr][3] = a.w;
        w[fr][4] = b.x; w[fr][5] = b.y; w[fr][6] = b.z; w[fr][7] = b.w;
    }
    float bias[8];
    {
        float4 a = *(const float4*)(b1 + f0);
        float4 b = *(const float4*)(b1 + f0 + 4);
        bias[0] = a.x; bias[1] = a.y; bias[2] = a.z; bias[3] = a.w;
        bias[4] = b.x; bias[5] = b.y; bias[6] = b.z; bias[7] = b.w;
    }
#pragma unroll 1
    for (int r = 0; r < QR2; ++r) {
        const float4 qa = *(const float4*)&qs[r][0];   // LDS broadcast
        const float4 qb = *(const float4*)&qs[r][4];
        float q[8] = { qa.x, qa.y, qa.z, qa.w, qb.x, qb.y, qb.z, qb.w };
        bf16x8 o;
#pragma unroll
        for (int fr = 0; fr < 8; ++fr) {
            float a = bias[fr];
#pragma unroll
            for (int i = 0; i < 8; ++i) a += q[i] * w[fr][i];
            o[fr] = (__bf16)fmaxf(a, 0.f);
        }
        *(bf16x8*)(H + (size_t)(r0 + r) * KDIM + f0) = o;
    }
}

// ---------------- C[M,N] = A[M,K] * B[N,K]^T + bias, bf16 MFMA ----------------
// Round-8 kernel verbatim -- best measured gemm (134 us, 1025 TF, MfmaUtil 44%,
// Occupancy 37%, FETCH 132 MB, 0 bank conflicts). Structure frozen:
//  - r1-r4 256-tile counted-vmcnt rewrites: within noise of this.
//  - launch_bounds(256,4): grid 1024 = exactly 4 blocks/CU resident (LDS
//    4x32KB=128KB, VGPR 64); cross-block MFMA covers per-tile barrier drains
//    (3->4 residency was -15 us).
//  - tile reshapes for >4 blocks/CU all worsen ds_read:MFMA ratio (0.5 ->
//    0.625-0.75) with LDS co-critical -> rejected on paper.
//  - plain C stores (r7: nt stores +48 us via partial-line HBM RMW).
// m97 structure: 128x128 block, 4 waves (2x2), each wave 64x64 = 4x4 of
// 16x16x32 MFMA. BK=64, 32 KB LDS.
// XCD-affine 1-D grid: xcd=id%8, s=id/8, bn=s%8 (FASTEST), bm=xcd*16+s/8.
// LDS XOR-swizzle in 16B units: phys(row, u) = u ^ (row & 7); source-side
// pre-swizzle on the global address (global_load_lds writes linearly).
__global__ __launch_bounds__(256, 4) void gemm_bt_kernel(const __bf16* __restrict__ A,
                                                         const __bf16* __restrict__ B,
                                                         const float* __restrict__ bias,
                                                         float* __restrict__ C) {
    __shared__ __align__(16) __bf16 Al[BM * BK];
    __shared__ __align__(16) __bf16 Bl[BN * BK];

    const int tid  = threadIdx.x;
    const int wave = tid >> 6;
    const int lane = tid & 63;
    const int id   = blockIdx.x;
    const int xcd  = id & 7;
    const int s    = id >> 3;
    const int bn   = s & 7;
    const int bm   = xcd * 16 + (s >> 3);

    // ---- staging: wave stages rows [wave*32, +32) of A and B, 4 chunks of 8 rows
    const int lr = lane >> 3;            // row within 8-row chunk
    const int ul = (lane & 7) ^ lr;      // logical 16B unit to source (swizzle)
    const __bf16* gA0 = A + (size_t)(bm * BM + wave * 32 + lr) * KDIM + ul * 8;
    const __bf16* gB0 = B + (size_t)(bn * BN + wave * 32 + lr) * KDIM + ul * 8;
    __bf16* lA0 = &Al[(wave * 32) * BK];
    __bf16* lB0 = &Bl[(wave * 32) * BK];

    // ---- fragment indices (16x16x32: lane holds [m=lane&15][k=(lane>>4)*8+j])
    const int ml = lane & 15;
    const int kq = lane >> 4;            // 0..3
    const int sw = lane & 7;             // row & 7 for fragment rows
    const int wm = (wave & 1) * 64;
    const int wn = (wave >> 1) * 64;

    f32x4 acc[4][4] = {};

    for (int kt = 0; kt < KDIM; kt += BK) {
        __syncthreads();   // previous tile's reads done before overwrite
#pragma unroll
        for (int c = 0; c < 4; ++c) {
            __builtin_amdgcn_global_load_lds((AS1 void*)(gA0 + (size_t)c * 8 * KDIM + kt),
                                             (AS3 void*)(lA0 + c * 8 * BK), 16, 0, 0);
            __builtin_amdgcn_global_load_lds((AS1 void*)(gB0 + (size_t)c * 8 * KDIM + kt),
                                             (AS3 void*)(lB0 + c * 8 * BK), 16, 0, 0);
        }
        __syncthreads();   // drains vmcnt -> tiles complete
#pragma unroll
        for (int st = 0; st < 2; ++st) {  // 2 k-steps of 32
            const int u = ((st * 4 + kq) ^ sw) * 8;
            bf16x8 afrag[4], bfrag[4];
#pragma unroll
            for (int i = 0; i < 4; ++i) {
                afrag[i] = *(const bf16x8*)&Al[(wm + i * 16 + ml) * BK + u];
                bfrag[i] = *(const bf16x8*)&Bl[(wn + i * 16 + ml) * BK + u];
            }
#pragma unroll
            for (int i = 0; i < 4; ++i)
#pragma unroll
                for (int j = 0; j < 4; ++j)
                    acc[i][j] = __builtin_amdgcn_mfma_f32_16x16x32_bf16(afrag[i], bfrag[j], acc[i][j], 0, 0, 0);
        }
    }

    // ---- epilogue: 16x16 C/D layout col=lane&15, row=(lane>>4)*4+reg
    const int cm0 = bm * BM + wm;
    const int cn0 = bn * BN + wn;
#pragma unroll
    for (int j = 0; j < 4; ++j) {
        const int col = cn0 + j * 16 + ml;
        const float bv = bias[col];
#pragma unroll
        for (int i = 0; i < 4; ++i) {
            const int row0 = cm0 + i * 16 + kq * 4;
#pragma unroll
            for (int r = 0; r < 4; ++r)
                C[(size_t)(row0 + r) * NDIM + col] = acc[i][j][r] + bv;
        }
    }
}

extern "C" void kernel_launch(void* const* d_in, const int* in_sizes, int n_in,
                              void* d_out, int out_size, void* d_ws, size_t ws_size,
                              hipStream_t stream) {
    const float* x     = (const float*)d_in[0];
    const float* theta = (const float*)d_in[1];
    const float* W1    = (const float*)d_in[2];
    const float* b1    = (const float*)d_in[3];
    const float* W2    = (const float*)d_in[4];
    const float* b2    = (const float*)d_in[5];
    float* out = (float*)d_out;

    __bf16* H   = (__bf16*)d_ws;                                    // 128 MiB
    __bf16* W2b = (__bf16*)((char*)d_ws + (size_t)MDIM * KDIM * 2); // + 8 MiB

    conv_w2_kernel<<<(KDIM * NDIM) / (256 * 8), 256, 0, stream>>>(W2, W2b);
    qh_kernel<<<(MDIM / QR2) * 2, 256, 0, stream>>>(x, theta, W1, b1, H);
    gemm_bt_kernel<<<(MDIM / BM) * (NDIM / BN), 256, 0, stream>>>(H, W2b, b2, out);
}